// Round 1
// baseline (375.570 us; speedup 1.0000x reference)
//
#include <hip/hip_runtime.h>
#include <hip/hip_bf16.h>

#define DM 512
#define BCN 2048
#define XPATCH ((size_t)BCN * 64 * DM)     // 67,108,864 floats

typedef float f32x4 __attribute__((ext_vector_type(4)));

__device__ __forceinline__ unsigned pack_bf16(float a, float b) {
    __hip_bfloat162 h = __float22bfloat162_rn(make_float2(a, b));
    return *reinterpret_cast<unsigned*>(&h);
}
__device__ __forceinline__ float2 unpack_bf16(unsigned p) {
    float2 r;
    r.x = __uint_as_float(p << 16);
    r.y = __uint_as_float(p & 0xffff0000u);
    return r;
}
__device__ __forceinline__ void fma4p(f32x4& a, float xv, float2 wa, float2 wb) {
    a.x = fmaf(xv, wa.x, a.x);
    a.y = fmaf(xv, wa.y, a.y);
    a.z = fmaf(xv, wb.x, a.z);
    a.w = fmaf(xv, wb.y, a.w);
}
__device__ __forceinline__ void fma4f(f32x4& a, float xv, f32x4 w) {
    a.x = fmaf(xv, w.x, a.x);
    a.y = fmaf(xv, w.y, a.y);
    a.z = fmaf(xv, w.z, a.z);
    a.w = fmaf(xv, w.w, a.w);
}

// One block per bc row (2048 blocks x 256 threads), 4 blocks/CU.
// LDS: w32 staged bf16 (32 KB) + x row (2 KB). Single barrier.
// Wave w: region parity pw = w&1, column half ch = w>>1.
// Each wave computes the 8 classifiers it consumes -> no A->B barrier,
// expert ids live in one packed SGPR.
// All out-stores nontemporal: 268 MB stream must not sweep the 4 MB/XCD L2
// (keeps w8/w16 + w32 source resident for the inner-loop loads).
__global__ __launch_bounds__(256, 4) void ape_fused(
    const float* __restrict__ x,
    const float* __restrict__ gumbel,
    const float* __restrict__ w1,
    const float* __restrict__ b1,
    const float* __restrict__ w2,
    const float* __restrict__ b2,
    const float* __restrict__ w8,
    const float* __restrict__ w16,
    const float* __restrict__ w32,
    float* __restrict__ out)
{
    __shared__ unsigned w32s[32 * 256];    // 32 KB: 32 rows x 256 bf16-pairs
    __shared__ float    xs[DM];            // 2 KB

    const int bc  = blockIdx.x;
    const int tid = threadIdx.x;

    // ---- stage x row (first 128 threads), nontemporal (zero reuse) ----
    if (tid < 128) {
        f32x4 v = __builtin_nontemporal_load(
            reinterpret_cast<const f32x4*>(x + (size_t)bc * DM) + tid);
        reinterpret_cast<f32x4*>(xs)[tid] = v;
    }

    // ---- stage w32 -> LDS bf16 (all threads, 16 float4 each) ----
    #pragma unroll
    for (int it = 0; it < 16; ++it) {
        int f4   = it * 256 + tid;         // 0..4095
        int row  = f4 >> 7;
        int col4 = f4 & 127;
        f32x4 v = reinterpret_cast<const f32x4*>(w32 + (size_t)row * DM)[col4];
        reinterpret_cast<uint2*>(w32s)[row * 128 + col4] =
            make_uint2(pack_bf16(v.x, v.y), pack_bf16(v.z, v.w));
    }
    __syncthreads();                       // the ONLY block-wide barrier

    const int lane = tid & 63;
    const int wv   = tid >> 6;
    const int pw   = wv & 1;               // region parity owned by this wave
    const int ch   = wv >> 1;              // column half owned by this wave

    // ---- Phase A: classifier, per-wave self-sufficient (8 regions) ----
    unsigned epack = 0;                    // 2 bits per region-slot
    {
        float w1r[32];
        #pragma unroll
        for (int q = 0; q < 32; ++q) w1r[q] = w1[q * 64 + lane];
        const float w2r0 = w2[lane * 3 + 0];
        const float w2r1 = w2[lane * 3 + 1];
        const float w2r2 = w2[lane * 3 + 2];
        const float b1r  = b1[lane];
        const float b20  = b2[0], b21 = b2[1], b22 = b2[2];

        #pragma unroll
        for (int p = 0; p < 8; ++p) {
            const int rr = p * 2 + pw;
            const float* xr = xs + rr * 32;
            float a = b1r;
            #pragma unroll
            for (int q = 0; q < 32; ++q) a = fmaf(xr[q], w1r[q], a);
            float h = fmaxf(a, 0.f);
            float p0 = h * w2r0, p1 = h * w2r1, p2 = h * w2r2;
            #pragma unroll
            for (int off = 1; off < 64; off <<= 1) {   // butterfly: all lanes get sum
                p0 += __shfl_xor(p0, off, 64);
                p1 += __shfl_xor(p1, off, 64);
                p2 += __shfl_xor(p2, off, 64);
            }
            const float* g = gumbel + ((size_t)bc * 16 + rr) * 3;
            float s0 = p0 + b20 + g[0];
            float s1 = p1 + b21 + g[1];
            float s2 = p2 + b22 + g[2];
            int best = 0; float bs = s0;
            if (s1 > bs) { bs = s1; best = 1; }
            if (s2 > bs) { best = 2; }
            epack |= (unsigned)best << (2 * p);
            if ((ch | lane) == 0)          // lane 0 of waves 0 and 1 only
                __builtin_nontemporal_store(
                    (float)best, out + XPATCH + (size_t)rr * BCN + bc);
        }
        epack = (unsigned)__builtin_amdgcn_readfirstlane((int)epack);  // -> SGPR
    }
    // NO second barrier: this wave consumes only what it computed.

    // ---- Phase B: expert embedding + PE ----
    const int cg = ch * 64 + lane;         // float4 column group 0..127
    const int c0 = cg * 4;
    const float kln = -9.210340371976184f / 256.0f;   // -ln(10000)/256
    const float dv0 = __expf((float)(cg * 2)     * kln);
    const float dv1 = __expf((float)(cg * 2 + 1) * kln);
    const uint2*  w32b = reinterpret_cast<const uint2*>(w32s) + cg;
    const f32x4*  w8b  = reinterpret_cast<const f32x4*>(w8)  + cg;
    const f32x4*  w16b = reinterpret_cast<const f32x4*>(w16) + cg;

    #pragma unroll 1
    for (int p = 0; p < 8; ++p) {
        const int rr = p * 2 + pw;
        const int e  = (int)((epack >> (2 * p)) & 3u);   // scalar, no LDS
        const int xo = rr * 32;
        f32x4 a0 = {0,0,0,0}, a1 = {0,0,0,0}, a2 = {0,0,0,0}, a3 = {0,0,0,0};

        if (e == 0) {                       // p=8: 4 distinct dots of len 8
            #pragma unroll
            for (int q = 0; q < 8; ++q) {
                f32x4 wvv = w8b[q * 128];
                fma4f(a0, xs[xo + q],      wvv);
                fma4f(a1, xs[xo + 8  + q], wvv);
                fma4f(a2, xs[xo + 16 + q], wvv);
                fma4f(a3, xs[xo + 24 + q], wvv);
            }
        } else if (e == 1) {                // p=16: rows 0..2 patch0, row 3 patch1
            #pragma unroll
            for (int q = 0; q < 16; ++q) {
                f32x4 wvv = w16b[q * 128];
                fma4f(a0, xs[xo + q],      wvv);
                fma4f(a3, xs[xo + 16 + q], wvv);
            }
            a1 = a0; a2 = a0;
        } else {                            // p=32: 1 dot of len 32 (LDS bf16)
            #pragma unroll
            for (int q = 0; q < 32; ++q) {
                uint2 pk = w32b[q * 128];
                float2 wa = unpack_bf16(pk.x), wb = unpack_bf16(pk.y);
                fma4p(a0, xs[xo + q], wa, wb);
            }
            a1 = a0; a2 = a0; a3 = a0;
        }

        const size_t ob = ((size_t)(bc * 64 + rr * 4)) * DM + c0;
        f32x4 av[4] = {a0, a1, a2, a3};
        #pragma unroll
        for (int t = 0; t < 4; ++t) {
            float sv0, cv0, sv1, cv1;
            const float pos = (float)(rr * 4 + t);
            __sincosf(pos * dv0, &sv0, &cv0);
            __sincosf(pos * dv1, &sv1, &cv1);
            f32x4 o;
            o.x = av[t].x + sv0;
            o.y = av[t].y + cv0;
            o.z = av[t].z + sv1;
            o.w = av[t].w + cv1;
            __builtin_nontemporal_store(
                o, reinterpret_cast<f32x4*>(out + ob + (size_t)t * DM));
        }
    }
}

extern "C" void kernel_launch(void* const* d_in, const int* in_sizes, int n_in,
                              void* d_out, int out_size, void* d_ws, size_t ws_size,
                              hipStream_t stream) {
    const float* x      = (const float*)d_in[0];
    const float* gumbel = (const float*)d_in[1];
    const float* w1     = (const float*)d_in[2];
    const float* b1     = (const float*)d_in[3];
    const float* w2     = (const float*)d_in[4];
    const float* b2     = (const float*)d_in[5];
    const float* w8     = (const float*)d_in[6];
    const float* w16    = (const float*)d_in[7];
    const float* w32    = (const float*)d_in[8];
    float* out = (float*)d_out;

    ape_fused<<<BCN, 256, 0, stream>>>(x, gumbel, w1, b1, w2, b2, w8, w16, w32, out);
}

// Round 2
// 313.785 us; speedup vs baseline: 1.1969x; 1.1969x over previous
//
#include <hip/hip_runtime.h>
#include <hip/hip_bf16.h>

#define DM 512
#define BCN 2048
#define XPATCH ((size_t)BCN * 64 * DM)     // 67,108,864 floats

typedef float f32x4 __attribute__((ext_vector_type(4)));

__device__ __forceinline__ unsigned pack_bf16(float a, float b) {
    __hip_bfloat162 h = __float22bfloat162_rn(make_float2(a, b));
    return *reinterpret_cast<unsigned*>(&h);
}
__device__ __forceinline__ float2 unpack_bf16(unsigned p) {
    float2 r;
    r.x = __uint_as_float(p << 16);
    r.y = __uint_as_float(p & 0xffff0000u);
    return r;
}
__device__ __forceinline__ void fma4p(f32x4& a, float xv, float2 wa, float2 wb) {
    a.x = fmaf(xv, wa.x, a.x);
    a.y = fmaf(xv, wa.y, a.y);
    a.z = fmaf(xv, wb.x, a.z);
    a.w = fmaf(xv, wb.y, a.w);
}

// Grid: 2048 blocks x 256 threads. Block = (bc-pair, column-half).
//   bid>>1 = bc pair, bid&1 = which 256 output columns.
// Waves: wv&1 = region parity, wv>>1 = which bc of the pair.
// ALL expert weights staged to LDS as bf16 (28 KB) + two x rows (4 KB) = 32 KB.
// Rationale: vmcnt counts loads AND stores in issue order. With w8/w16 read
// from global inside the region loop, the pre-FMA s_waitcnt vmcnt(0) forced
// every iteration to drain the 4 streaming stores of the previous region
// (store-retire latency on the critical path, 8x/wave). With weights in LDS,
// the loop waits only on lgkmcnt; the 268 MB store stream is fire-and-forget.
// Stores are REGULAR (nontemporal measured -80 us in R1: NT bypasses L2
// write combining, ~2 TB/s vs ~6).
__global__ __launch_bounds__(256, 4) void ape_fused(
    const float* __restrict__ x,
    const float* __restrict__ gumbel,
    const float* __restrict__ w1,
    const float* __restrict__ b1,
    const float* __restrict__ w2,
    const float* __restrict__ b2,
    const float* __restrict__ w8,
    const float* __restrict__ w16,
    const float* __restrict__ w32,
    float* __restrict__ out)
{
    __shared__ uint2 w32s[32 * 64];        // 16 KB: rows x 64 col4-groups (bf16 pairs)
    __shared__ uint2 w16s[16 * 64];        //  8 KB
    __shared__ uint2 w8s [ 8 * 64];        //  4 KB
    __shared__ float xs[2 * DM];           //  4 KB: two bc rows

    const int bid    = blockIdx.x;
    const int tid    = threadIdx.x;
    const int bcpair = bid >> 1;
    const int half   = bid & 1;            // which 256-column half of out
    const int bc0    = bcpair * 2;

    // ---- stage two x rows (full rows: classifier needs all 512) ----
    {
        const int row = tid >> 7, col4 = tid & 127;
        f32x4 v = reinterpret_cast<const f32x4*>(x + (size_t)(bc0 + row) * DM)[col4];
        reinterpret_cast<f32x4*>(xs + row * DM)[col4] = v;
    }
    // ---- stage w32 half-columns -> LDS bf16 (2048 uint2) ----
    #pragma unroll
    for (int it = 0; it < 8; ++it) {
        int idx = it * 256 + tid;
        int row = idx >> 6, cl = idx & 63;
        f32x4 v = reinterpret_cast<const f32x4*>(w32 + (size_t)row * DM)[half * 64 + cl];
        w32s[row * 64 + cl] = make_uint2(pack_bf16(v.x, v.y), pack_bf16(v.z, v.w));
    }
    // ---- stage w16 half-columns (1024 uint2) ----
    #pragma unroll
    for (int it = 0; it < 4; ++it) {
        int idx = it * 256 + tid;
        int row = idx >> 6, cl = idx & 63;
        f32x4 v = reinterpret_cast<const f32x4*>(w16 + (size_t)row * DM)[half * 64 + cl];
        w16s[row * 64 + cl] = make_uint2(pack_bf16(v.x, v.y), pack_bf16(v.z, v.w));
    }
    // ---- stage w8 half-columns (512 uint2) ----
    #pragma unroll
    for (int it = 0; it < 2; ++it) {
        int idx = it * 256 + tid;
        int row = idx >> 6, cl = idx & 63;
        f32x4 v = reinterpret_cast<const f32x4*>(w8 + (size_t)row * DM)[half * 64 + cl];
        w8s[row * 64 + cl] = make_uint2(pack_bf16(v.x, v.y), pack_bf16(v.z, v.w));
    }
    __syncthreads();                       // the ONLY block-wide barrier

    const int lane  = tid & 63;
    const int wv    = tid >> 6;
    const int pw    = wv & 1;              // region parity owned by this wave
    const int bcsel = wv >> 1;             // which bc of the pair
    const int bc    = bc0 + bcsel;
    const float* xb = xs + bcsel * DM;

    // ---- Phase A: classifier, per-wave self-sufficient (8 regions) ----
    unsigned epack = 0;                    // 2 bits per region-slot
    {
        float w1r[32];
        #pragma unroll
        for (int q = 0; q < 32; ++q) w1r[q] = w1[q * 64 + lane];
        const float w2r0 = w2[lane * 3 + 0];
        const float w2r1 = w2[lane * 3 + 1];
        const float w2r2 = w2[lane * 3 + 2];
        const float b1r  = b1[lane];
        const float b20  = b2[0], b21 = b2[1], b22 = b2[2];

        // preload gumbel for all 8 owned regions (lane p holds region p*2+pw)
        float g0 = 0.f, g1 = 0.f, g2 = 0.f;
        if (lane < 8) {
            const float* g = gumbel + ((size_t)bc * 16 + (lane * 2 + pw)) * 3;
            g0 = g[0]; g1 = g[1]; g2 = g[2];
        }

        #pragma unroll
        for (int p = 0; p < 8; ++p) {
            const int rr = p * 2 + pw;
            const float* xr = xb + rr * 32;
            float a = b1r;
            #pragma unroll
            for (int q = 0; q < 32; ++q) a = fmaf(xr[q], w1r[q], a);
            float h = fmaxf(a, 0.f);
            float p0 = h * w2r0, p1 = h * w2r1, p2 = h * w2r2;
            #pragma unroll
            for (int off = 1; off < 64; off <<= 1) {   // butterfly: all lanes get sum
                p0 += __shfl_xor(p0, off, 64);
                p1 += __shfl_xor(p1, off, 64);
                p2 += __shfl_xor(p2, off, 64);
            }
            float s0 = p0 + b20 + __shfl(g0, p, 64);
            float s1 = p1 + b21 + __shfl(g1, p, 64);
            float s2 = p2 + b22 + __shfl(g2, p, 64);
            int best = 0; float bs = s0;
            if (s1 > bs) { bs = s1; best = 1; }
            if (s2 > bs) { best = 2; }
            epack |= (unsigned)best << (2 * p);
            if ((half | lane) == 0)        // one block-half, lane 0 writes preds
                out[XPATCH + (size_t)rr * BCN + bc] = (float)best;
        }
        epack = (unsigned)__builtin_amdgcn_readfirstlane((int)epack);  // -> SGPR
    }
    // NO second barrier: this wave consumes only what it computed.

    // ---- Phase B: expert embedding + PE (LDS reads only; stores unwaited) ----
    const int cgg = half * 64 + lane;      // global float4 column group 0..127
    const int c0  = cgg * 4;
    const float kln = -9.210340371976184f / 256.0f;   // -ln(10000)/256
    const float dv0 = __expf((float)(cgg * 2)     * kln);
    const float dv1 = __expf((float)(cgg * 2 + 1) * kln);
    const uint2* w32b = w32s + lane;
    const uint2* w16b = w16s + lane;
    const uint2* w8b  = w8s  + lane;

    #pragma unroll 1
    for (int p = 0; p < 8; ++p) {
        const int rr = p * 2 + pw;
        const int e  = (int)((epack >> (2 * p)) & 3u);   // scalar branch
        const int xo = rr * 32;
        f32x4 a0 = {0,0,0,0}, a1 = {0,0,0,0}, a2 = {0,0,0,0}, a3 = {0,0,0,0};

        if (e == 0) {                       // p=8: 4 distinct dots of len 8
            #pragma unroll
            for (int q = 0; q < 8; ++q) {
                uint2 pk = w8b[q * 64];
                float2 wa = unpack_bf16(pk.x), wb = unpack_bf16(pk.y);
                fma4p(a0, xb[xo + q],      wa, wb);
                fma4p(a1, xb[xo + 8  + q], wa, wb);
                fma4p(a2, xb[xo + 16 + q], wa, wb);
                fma4p(a3, xb[xo + 24 + q], wa, wb);
            }
        } else if (e == 1) {                // p=16: rows 0..2 patch0, row 3 patch1
            #pragma unroll
            for (int q = 0; q < 16; ++q) {
                uint2 pk = w16b[q * 64];
                float2 wa = unpack_bf16(pk.x), wb = unpack_bf16(pk.y);
                fma4p(a0, xb[xo + q],      wa, wb);
                fma4p(a3, xb[xo + 16 + q], wa, wb);
            }
            a1 = a0; a2 = a0;
        } else {                            // p=32: 1 dot of len 32
            #pragma unroll
            for (int q = 0; q < 32; ++q) {
                uint2 pk = w32b[q * 64];
                float2 wa = unpack_bf16(pk.x), wb = unpack_bf16(pk.y);
                fma4p(a0, xb[xo + q], wa, wb);
            }
            a1 = a0; a2 = a0; a3 = a0;
        }

        const size_t ob = ((size_t)(bc * 64 + rr * 4)) * DM + c0;
        f32x4 av[4] = {a0, a1, a2, a3};
        #pragma unroll
        for (int t = 0; t < 4; ++t) {
            float sv0, cv0, sv1, cv1;
            const float pos = (float)(rr * 4 + t);
            __sincosf(pos * dv0, &sv0, &cv0);
            __sincosf(pos * dv1, &sv1, &cv1);
            f32x4 o;
            o.x = av[t].x + sv0;
            o.y = av[t].y + cv0;
            o.z = av[t].z + sv1;
            o.w = av[t].w + cv1;
            *reinterpret_cast<f32x4*>(out + ob + (size_t)t * DM) = o;
        }
    }
}

extern "C" void kernel_launch(void* const* d_in, const int* in_sizes, int n_in,
                              void* d_out, int out_size, void* d_ws, size_t ws_size,
                              hipStream_t stream) {
    const float* x      = (const float*)d_in[0];
    const float* gumbel = (const float*)d_in[1];
    const float* w1     = (const float*)d_in[2];
    const float* b1     = (const float*)d_in[3];
    const float* w2     = (const float*)d_in[4];
    const float* b2     = (const float*)d_in[5];
    const float* w8     = (const float*)d_in[6];
    const float* w16    = (const float*)d_in[7];
    const float* w32    = (const float*)d_in[8];
    float* out = (float*)d_out;

    ape_fused<<<BCN, 256, 0, stream>>>(x, gumbel, w1, b1, w2, b2, w8, w16, w32, out);
}